// Round 9
// baseline (162.109 us; speedup 1.0000x reference)
//
#include <hip/hip_runtime.h>
#include <math.h>

#define DD    512
#define NN    32768      // B*L nodes
#define EE    262144     // edges (without self loops)

typedef float f32x4 __attribute__((ext_vector_type(4)));
typedef __bf16 bf16x8 __attribute__((ext_vector_type(8)));
typedef __bf16 bf16x4 __attribute__((ext_vector_type(4)));

// ---------------- CSR build ----------------
__global__ void k_zero(int* __restrict__ cnt) {
    int i = blockIdx.x * 256 + threadIdx.x;
    if (i < NN) cnt[i] = 0;
}

__global__ void k_count(const int* __restrict__ dst, int* __restrict__ cnt) {
    int e = blockIdx.x * 256 + threadIdx.x;
    if (e < EE) atomicAdd(&cnt[dst[e]], 1);
}

__global__ __launch_bounds__(1024) void k_scan(
    const int* __restrict__ cnt, int* __restrict__ offs,
    int* __restrict__ cursor, float* __restrict__ dinv)
{
    __shared__ int part[1024];
    int t = threadIdx.x;
    int base = t * 32;
    int local[32];
    int s = 0;
#pragma unroll
    for (int i = 0; i < 32; ++i) { local[i] = s; s += cnt[base + i]; }
    part[t] = s;
    __syncthreads();
    for (int off = 1; off < 1024; off <<= 1) {
        int v = (t >= off) ? part[t - off] : 0;
        __syncthreads();
        part[t] += v;
        __syncthreads();
    }
    int prev = (t == 0) ? 0 : part[t - 1];
#pragma unroll
    for (int i = 0; i < 32; ++i) {
        int o = prev + local[i];
        offs[base + i] = o;
        cursor[base + i] = o;
        dinv[base + i] = rsqrtf((float)cnt[base + i] + 1.0f);
    }
    if (t == 1023) offs[NN] = part[1023];
}

__global__ void k_fill(const int* __restrict__ src, const int* __restrict__ dst,
                       int* __restrict__ cursor, int* __restrict__ csr) {
    int e = blockIdx.x * 256 + threadIdx.x;
    if (e < EE) {
        int d = dst[e];
        int p = atomicAdd(&cursor[d], 1);
        csr[p] = src[e];
    }
}

// ---------------- weight transpose + convert: Wt[n][k] = (bf16)W[k][n] ----------------
__global__ __launch_bounds__(256) void k_wt(const float* __restrict__ W1, const float* __restrict__ Wg,
                                            __bf16* __restrict__ W1t, __bf16* __restrict__ Wgt) {
    __shared__ float tile[32][33];
    const float* W = blockIdx.z ? Wg : W1;
    __bf16* Wt = blockIdx.z ? Wgt : W1t;
    int x0 = blockIdx.x * 32;   // n block
    int y0 = blockIdx.y * 32;   // k block
    int tx = threadIdx.x;       // 0..31
    for (int j = threadIdx.y; j < 32; j += 8)
        tile[j][tx] = W[(size_t)(y0 + j) * DD + x0 + tx];
    __syncthreads();
    for (int j = threadIdx.y; j < 32; j += 8)
        Wt[(size_t)(x0 + j) * DD + y0 + tx] = (__bf16)tile[tx][j];
}

// ---------------- bf16 MFMA GEMM, 64x128 tile, BK=32, low-register / high-occupancy ----------------
// Per-wave tile 32x64: acc = 2x4 frags = 32 AGPR (vs 64), targeting 4-5 waves/SIMD.
// MODE 1: A fp32 (text), reg-staged + inline cvt; out = PReLU(BN(A@B+b1)) bf16
// MODE 2: A bf16 (h), global_load_lds;            out = (A@B)*dinv[row]  bf16
// Counted-vmcnt double-buffer: staging loads for tile k+1 stay in flight across barriers.
// Grid: 2048 blocks, XCD-affinity swizzle (4 n-tiles of an m-panel consecutive on one XCD).
template <int MODE>
__global__ __launch_bounds__(256) void k_gemm_mfma(
    const void* __restrict__ Ap,
    const __bf16* __restrict__ Bt,
    __bf16* __restrict__ Cout,
    const float* __restrict__ bias,
    const float* __restrict__ gamma, const float* __restrict__ beta,
    const float* __restrict__ mean, const float* __restrict__ var,
    const float* __restrict__ alphap,
    const float* __restrict__ dinv)
{
    __shared__ __bf16 As[2][64 * 32];    // 4 KB each
    __shared__ __bf16 Bs[2][128 * 32];   // 8 KB each   (total 24 KB)

    const int tid  = threadIdx.x;
    const int lane = tid & 63;
    const int w    = tid >> 6;
    const int wm   = (w >> 1) * 32;      // wave row offset (0/32)
    const int wn   = (w & 1) * 64;       // wave col offset (0/64)
    const int work = ((blockIdx.x & 7) << 8) + (blockIdx.x >> 3);  // bijective, 2048
    const int m0   = (work >> 2) * 64;
    const int n0   = (work & 3) * 128;

    f32x4 acc[2][4] = {};
    float4 fa[2];    // MODE1 A-staging registers (8 floats = one bf16x8 slot)

    auto stageB = [&](int bb, int k0) {
#pragma unroll
        for (int rd = 0; rd < 2; ++rd) {
            int cbase = rd * 256 + w * 64;
            int cidx = cbase + lane;
            int r = cidx >> 2, s = cidx & 3;
            int c = s ^ ((r >> 1) & 3);
            const __bf16* gb = Bt + (size_t)(n0 + r) * DD + k0 + c * 8;
            __builtin_amdgcn_global_load_lds(
                (const __attribute__((address_space(1))) unsigned int*)gb,
                (__attribute__((address_space(3))) unsigned int*)(&Bs[bb][cbase * 8]), 16, 0, 0);
        }
    };
    auto stageA_lds = [&](int bb, int k0) {    // MODE2: 64x32 bf16 = 256 slots = 1 instr
        const __bf16* A = (const __bf16*)Ap;
        int cbase = w * 64;
        int cidx = cbase + lane;
        int r = cidx >> 2, s = cidx & 3;
        int c = s ^ ((r >> 1) & 3);
        const __bf16* ga = A + (size_t)(m0 + r) * DD + k0 + c * 8;
        __builtin_amdgcn_global_load_lds(
            (const __attribute__((address_space(1))) unsigned int*)ga,
            (__attribute__((address_space(3))) unsigned int*)(&As[bb][cbase * 8]), 16, 0, 0);
    };
    auto loadA = [&](int k0) {                 // MODE1: thread owns slot tid (8 fp32)
        const float* A = (const float*)Ap;
        int r = tid >> 2, s = tid & 3;
        int c = s ^ ((r >> 1) & 3);
        const float* ga = A + (size_t)(m0 + r) * DD + k0 + c * 8;
        fa[0] = *(const float4*)ga;
        fa[1] = *(const float4*)(ga + 4);
    };
    auto writeA = [&](int bb) {
        bf16x8 o;
        o[0] = (__bf16)fa[0].x; o[1] = (__bf16)fa[0].y;
        o[2] = (__bf16)fa[0].z; o[3] = (__bf16)fa[0].w;
        o[4] = (__bf16)fa[1].x; o[5] = (__bf16)fa[1].y;
        o[6] = (__bf16)fa[1].z; o[7] = (__bf16)fa[1].w;
        *(bf16x8*)&As[bb][tid * 8] = o;
    };

    // --- prologue: tile 0 into buffer 0 ---
    if constexpr (MODE == 1) {
        loadA(0);
        stageB(0, 0);
        writeA(0);                                           // compiler waits fa's vmcnt
        asm volatile("s_waitcnt lgkmcnt(0)" ::: "memory");
    } else {
        stageA_lds(0, 0);
        stageB(0, 0);
    }

    // --- K loop: 16 steps, fully unrolled; raw barriers + counted vmcnt ---
#pragma unroll
    for (int kt = 0; kt < 16; ++kt) {
        const int cur = kt & 1;
        const int nxt = cur ^ 1;
        const int k1  = (kt + 1) * 32;

        // 1) issue next tile's staging (stays in flight across barriers)
        if (kt < 15) {
            if constexpr (MODE == 1) { loadA(k1); stageB(nxt, k1); }
            else                     { stageA_lds(nxt, k1); stageB(nxt, k1); }
        }

        // 2) wait ONLY current tile's staging loads (oldest), then barrier
        if constexpr (MODE == 1) {
            if (kt < 15) asm volatile("s_waitcnt vmcnt(4)" ::: "memory");
            else         asm volatile("s_waitcnt vmcnt(0)" ::: "memory");
        } else {
            if (kt < 15) asm volatile("s_waitcnt vmcnt(3)" ::: "memory");
            else         asm volatile("s_waitcnt vmcnt(0)" ::: "memory");
        }
        __builtin_amdgcn_s_barrier();                 // B1: cur tile ready
        asm volatile("" ::: "memory");

        // 3) frags of current tile
        bf16x8 af[2], bfr[4];
#pragma unroll
        for (int m = 0; m < 2; ++m) {
            int r = wm + m * 16 + (lane & 15);
            int s = (lane >> 4) ^ ((r >> 1) & 3);
            af[m] = *(const bf16x8*)&As[cur][r * 32 + s * 8];
        }
#pragma unroll
        for (int n = 0; n < 4; ++n) {
            int q = wn + n * 16 + (lane & 15);
            int sq = (lane >> 4) ^ ((q >> 1) & 3);
            bfr[n] = *(const bf16x8*)&Bs[cur][q * 32 + sq * 8];
        }

        // 4) compute (8 MFMA)
#pragma unroll
        for (int m = 0; m < 2; ++m)
#pragma unroll
            for (int n = 0; n < 4; ++n)
                acc[m][n] = __builtin_amdgcn_mfma_f32_16x16x32_bf16(af[m], bfr[n], acc[m][n], 0, 0, 0);

        // 5) MODE1: convert+write next A regs into next buffer, drain ds_writes
        if constexpr (MODE == 1) {
            if (kt < 15) writeA(nxt);
            asm volatile("s_waitcnt lgkmcnt(0)" ::: "memory");
        }

        // 6) B2: all waves done reading cur buffer
        asm volatile("" ::: "memory");
        __builtin_amdgcn_s_barrier();
        asm volatile("" ::: "memory");
    }

    // --- epilogue: C/D layout col = lane&15, row = (lane>>4)*4 + j ---
    float alpha = (MODE == 1) ? alphap[0] : 0.0f;
#pragma unroll
    for (int m = 0; m < 2; ++m) {
        int row_base = m0 + wm + m * 16 + ((lane >> 4) << 2);
#pragma unroll
        for (int n = 0; n < 4; ++n) {
            int col = n0 + wn + n * 16 + (lane & 15);
#pragma unroll
            for (int j = 0; j < 4; ++j) {
                int row = row_base + j;
                float x = acc[m][n][j];
                if (MODE == 1) {
                    x += bias[col];
                    x = (x - mean[col]) * rsqrtf(var[col] + 1e-5f) * gamma[col] + beta[col];
                    x = (x >= 0.0f) ? x : alpha * x;
                } else {
                    x *= dinv[row];
                }
                Cout[(size_t)row * DD + col] = (__bf16)x;
            }
        }
    }
}

// ---------------- fused gather + dinv + bias + PReLU + L2 norm + residual ----------------
__global__ __launch_bounds__(256) void k_gather_final(
    const int* __restrict__ offs, const int* __restrict__ csr,
    const __bf16* __restrict__ xws, const float* __restrict__ dinv,
    const float* __restrict__ bg, const float* __restrict__ alpha2,
    const float* __restrict__ text, float* __restrict__ out)
{
    int blk = blockIdx.x;                              // 0..8191
    int sb  = ((blk & 7) << 10) + (blk >> 3);          // XCD-chunked (bijective)
    int wave = threadIdx.x >> 6;
    int lane = threadIdx.x & 63;
    int node = sb * 4 + wave;
    int c = lane * 8;
    int beg = offs[node], end = offs[node + 1];
    int ne = end - beg;

    bf16x8 sv = *(const bf16x8*)(xws + (size_t)node * DD + c);   // self loop
    float a[8];
#pragma unroll
    for (int i = 0; i < 8; ++i) a[i] = (float)sv[i];

    int k = 0;
    for (; k + 4 <= ne; k += 4) {
        int s0 = csr[beg + k + 0];
        int s1 = csr[beg + k + 1];
        int s2 = csr[beg + k + 2];
        int s3 = csr[beg + k + 3];
        bf16x8 v0 = *(const bf16x8*)(xws + (size_t)s0 * DD + c);
        bf16x8 v1 = *(const bf16x8*)(xws + (size_t)s1 * DD + c);
        bf16x8 v2 = *(const bf16x8*)(xws + (size_t)s2 * DD + c);
        bf16x8 v3 = *(const bf16x8*)(xws + (size_t)s3 * DD + c);
#pragma unroll
        for (int i = 0; i < 8; ++i)
            a[i] += (float)v0[i] + (float)v1[i] + (float)v2[i] + (float)v3[i];
    }
    for (; k < ne; ++k) {
        int s = csr[beg + k];
        bf16x8 v = *(const bf16x8*)(xws + (size_t)s * DD + c);
#pragma unroll
        for (int i = 0; i < 8; ++i) a[i] += (float)v[i];
    }

    float di = dinv[node];
    float al = alpha2[0];
    float g[8];
    float ss = 0.0f;
#pragma unroll
    for (int i = 0; i < 8; ++i) {
        float x = a[i] * di + bg[c + i];
        x = (x >= 0.0f) ? x : al * x;
        g[i] = x;
        ss += x * x;
    }
#pragma unroll
    for (int off = 1; off < 64; off <<= 1) ss += __shfl_xor(ss, off, 64);
    float inv = 1.0f / fmaxf(sqrtf(ss), 1e-12f);

    float4 t0 = *(const float4*)(text + (size_t)node * DD + c);
    float4 t1 = *(const float4*)(text + (size_t)node * DD + c + 4);
    float4 o0, o1;
    o0.x = g[0] * inv + t0.x; o0.y = g[1] * inv + t0.y;
    o0.z = g[2] * inv + t0.z; o0.w = g[3] * inv + t0.w;
    o1.x = g[4] * inv + t1.x; o1.y = g[5] * inv + t1.y;
    o1.z = g[6] * inv + t1.z; o1.w = g[7] * inv + t1.w;
    *(float4*)(out + (size_t)node * DD + c)     = o0;
    *(float4*)(out + (size_t)node * DD + c + 4) = o1;
}

extern "C" void kernel_launch(void* const* d_in, const int* in_sizes, int n_in,
                              void* d_out, int out_size, void* d_ws, size_t ws_size,
                              hipStream_t stream) {
    const float* text   = (const float*)d_in[0];
    const int*   esrc   = (const int*)d_in[1];
    const int*   edst   = (const int*)d_in[2];
    const float* W1     = (const float*)d_in[3];
    const float* b1     = (const float*)d_in[4];
    const float* gamma  = (const float*)d_in[5];
    const float* beta   = (const float*)d_in[6];
    const float* rmean  = (const float*)d_in[7];
    const float* rvar   = (const float*)d_in[8];
    const float* alpha1 = (const float*)d_in[9];
    const float* Wg     = (const float*)d_in[10];
    const float* bg     = (const float*)d_in[11];
    const float* alpha2 = (const float*)d_in[12];
    float* out = (float*)d_out;

    // workspace layout (~66.5 MiB)
    char* p = (char*)d_ws;
    auto alloc = [&](size_t bytes) { char* r = p; p += (bytes + 255) & ~(size_t)255; return r; };
    int*    cnt     = (int*)alloc((size_t)NN * 4);
    int*    offs    = (int*)alloc((size_t)(NN + 1) * 4);
    int*    cursor  = (int*)alloc((size_t)NN * 4);
    float*  dinv    = (float*)alloc((size_t)NN * 4);
    int*    csr     = (int*)alloc((size_t)EE * 4);
    __bf16* W1t     = (__bf16*)alloc((size_t)DD * DD * 2);
    __bf16* Wgt     = (__bf16*)alloc((size_t)DD * DD * 2);
    __bf16* h_bf    = (__bf16*)alloc((size_t)NN * DD * 2);
    __bf16* xws     = (__bf16*)alloc((size_t)NN * DD * 2);

    // 1) CSR build + dinv
    k_zero<<<NN / 256, 256, 0, stream>>>(cnt);
    k_count<<<EE / 256, 256, 0, stream>>>(edst, cnt);
    k_scan<<<1, 1024, 0, stream>>>(cnt, offs, cursor, dinv);
    k_fill<<<EE / 256, 256, 0, stream>>>(esrc, edst, cursor, csr);

    // 2) weights -> bf16 [n][k]
    k_wt<<<dim3(16, 16, 2), dim3(32, 8), 0, stream>>>(W1, Wg, W1t, Wgt);

    // 3) h = PReLU(BN(text@W1 + b1))   [fp32 A inline-cvt, bf16 out]
    k_gemm_mfma<1><<<2048, 256, 0, stream>>>(text, W1t, h_bf, b1, gamma, beta, rmean, rvar, alpha1, nullptr);

    // 4) xws = (h@Wg) * dinv[row]     [bf16 out]
    k_gemm_mfma<2><<<2048, 256, 0, stream>>>(h_bf, Wgt, xws, nullptr, nullptr, nullptr, nullptr, nullptr, nullptr, dinv);

    // 5) fused gather + epilogue + L2 norm + residual
    k_gather_final<<<NN / 4, 256, 0, stream>>>(offs, csr, xws, dinv, bg, alpha2, text, out);
}

// Round 10
// 142.639 us; speedup vs baseline: 1.1365x; 1.1365x over previous
//
#include <hip/hip_runtime.h>
#include <math.h>

#define DD    512
#define NN    32768      // B*L nodes
#define EE    262144     // edges (without self loops)

typedef float f32x4 __attribute__((ext_vector_type(4)));
typedef __bf16 bf16x8 __attribute__((ext_vector_type(8)));

#define AS1 __attribute__((address_space(1)))
#define AS3 __attribute__((address_space(3)))

// ---------------- CSR build ----------------
__global__ void k_zero(int* __restrict__ cnt) {
    int i = blockIdx.x * 256 + threadIdx.x;
    if (i < NN) cnt[i] = 0;
}

__global__ void k_count(const int* __restrict__ dst, int* __restrict__ cnt) {
    int e = blockIdx.x * 256 + threadIdx.x;
    if (e < EE) atomicAdd(&cnt[dst[e]], 1);
}

__global__ __launch_bounds__(1024) void k_scan(
    const int* __restrict__ cnt, int* __restrict__ offs,
    int* __restrict__ cursor, float* __restrict__ dinv)
{
    __shared__ int part[1024];
    int t = threadIdx.x;
    int base = t * 32;
    int local[32];
    int s = 0;
#pragma unroll
    for (int i = 0; i < 32; ++i) { local[i] = s; s += cnt[base + i]; }
    part[t] = s;
    __syncthreads();
    for (int off = 1; off < 1024; off <<= 1) {
        int v = (t >= off) ? part[t - off] : 0;
        __syncthreads();
        part[t] += v;
        __syncthreads();
    }
    int prev = (t == 0) ? 0 : part[t - 1];
#pragma unroll
    for (int i = 0; i < 32; ++i) {
        int o = prev + local[i];
        offs[base + i] = o;
        cursor[base + i] = o;
        dinv[base + i] = rsqrtf((float)cnt[base + i] + 1.0f);
    }
    if (t == 1023) offs[NN] = part[1023];
}

__global__ void k_fill(const int* __restrict__ src, const int* __restrict__ dst,
                       int* __restrict__ cursor, int* __restrict__ csr) {
    int e = blockIdx.x * 256 + threadIdx.x;
    if (e < EE) {
        int d = dst[e];
        int p = atomicAdd(&cursor[d], 1);
        csr[p] = src[e];
    }
}

// ---------------- weight transpose + convert: Wt[n][k] = (bf16)W[k][n] ----------------
__global__ __launch_bounds__(256) void k_wt(const float* __restrict__ W1, const float* __restrict__ Wg,
                                            __bf16* __restrict__ W1t, __bf16* __restrict__ Wgt) {
    __shared__ float tile[32][33];
    const float* W = blockIdx.z ? Wg : W1;
    __bf16* Wt = blockIdx.z ? Wgt : W1t;
    int x0 = blockIdx.x * 32;   // n block
    int y0 = blockIdx.y * 32;   // k block
    int tx = threadIdx.x;       // 0..31
    for (int j = threadIdx.y; j < 32; j += 8)
        tile[j][tx] = W[(size_t)(y0 + j) * DD + x0 + tx];
    __syncthreads();
    for (int j = threadIdx.y; j < 32; j += 8)
        Wt[(size_t)(x0 + j) * DD + y0 + tx] = (__bf16)tile[tx][j];
}

// ---------------- weight-stationary bf16 MFMA GEMM ----------------
// W slice held in REGISTERS (wave: 32 cols x 512 K = 32 bf16x8 frags = 128 VGPR).
// Block: 8 waves x 32 cols = 256-col n-slice; 256 rows via 8 m-tiles of 32.
// Per m-tile: stage A-slab [32 rows x 512 K] into dbuf LDS (swizzled c^(r&7)),
// then full-K register loop: 16x(2 ds_read_b128 + 4 MFMA). ONE barrier per m-tile;
// its vmcnt(0) drain is free (next-slab loads issued a full m-tile earlier).
// MODE 1: A fp32 (text), reg-stage + cvt; out = PReLU(BN(A@W1+b1)) bf16
// MODE 2: A bf16 (h), pre-swizzled-source global_load_lds; out = A@Wg bf16 (unscaled)
template <int MODE>
__global__ __launch_bounds__(512, 2) void k_gemm_w(
    const void* __restrict__ Ap,
    const __bf16* __restrict__ Wt,
    __bf16* __restrict__ Cout,
    const float* __restrict__ bias,
    const float* __restrict__ gamma, const float* __restrict__ beta,
    const float* __restrict__ mean, const float* __restrict__ var,
    const float* __restrict__ alphap)
{
    __shared__ __bf16 slab[2][32 * DD];   // 2 x 32KB

    const int t    = threadIdx.x;
    const int lane = t & 63;
    const int wv   = t >> 6;
    const int work = ((blockIdx.x & 7) << 5) + (blockIdx.x >> 3);  // bijective 256; XCD-affine
    const int nsl  = work & 1;
    const int mb   = work >> 1;
    const int mbase   = mb * 256;
    const int colbase = nsl * 256 + wv * 32;

    // ---- one-time: W fragments into registers ----
    bf16x8 wf[2][16];
#pragma unroll
    for (int C = 0; C < 2; ++C)
#pragma unroll
        for (int kf = 0; kf < 16; ++kf) {
            int col = colbase + C * 16 + (lane & 15);
            wf[C][kf] = *(const bf16x8*)(Wt + (size_t)col * DD + kf * 32 + (lane >> 4) * 8);
        }

    // ---- one-time: BN/PReLU per-col constants (MODE1) ----
    float s0 = 0, s1 = 0, t0 = 0, t1 = 0, al = 0;
    if constexpr (MODE == 1) {
        int c0 = colbase + (lane & 15), c1 = c0 + 16;
        float r0 = rsqrtf(var[c0] + 1e-5f), r1 = rsqrtf(var[c1] + 1e-5f);
        s0 = gamma[c0] * r0;  s1 = gamma[c1] * r1;
        t0 = (bias[c0] - mean[c0]) * s0 + beta[c0];
        t1 = (bias[c1] - mean[c1]) * s1 + beta[c1];
        al = alphap[0];
    }

    float4 fa[4][2];   // MODE1 staging regs (4 chunks x 8 fp32)

    auto loadA1 = [&](int mt) {        // MODE1: global fp32 -> regs
        const float* A = (const float*)Ap;
#pragma unroll
        for (int q = 0; q < 4; ++q) {
            int ci = q * 512 + t;
            int r = ci >> 6, c = ci & 63;
            const float* g = A + (size_t)(mbase + mt * 32 + r) * DD + c * 8;
            fa[q][0] = *(const float4*)g;
            fa[q][1] = *(const float4*)(g + 4);
        }
    };
    auto writeA1 = [&](int bb) {       // cvt + swizzled ds_write
#pragma unroll
        for (int q = 0; q < 4; ++q) {
            int ci = q * 512 + t;
            int r = ci >> 6, c = ci & 63;
            bf16x8 o;
            o[0] = (__bf16)fa[q][0].x; o[1] = (__bf16)fa[q][0].y;
            o[2] = (__bf16)fa[q][0].z; o[3] = (__bf16)fa[q][0].w;
            o[4] = (__bf16)fa[q][1].x; o[5] = (__bf16)fa[q][1].y;
            o[6] = (__bf16)fa[q][1].z; o[7] = (__bf16)fa[q][1].w;
            *(bf16x8*)&slab[bb][r * DD + (c ^ (r & 7)) * 8] = o;
        }
    };
    auto stage2 = [&](int bb, int mt) { // MODE2: gload_lds, pre-swizzled source
        const __bf16* A = (const __bf16*)Ap;
#pragma unroll
        for (int q = 0; q < 4; ++q) {
            int ci = q * 512 + wv * 64 + lane;
            int r = ci >> 6, c = ci & 63;
            int cl = c ^ (r & 7);   // inverse swizzle on SOURCE, linear dest
            const __bf16* g = A + (size_t)(mbase + mt * 32 + r) * DD + cl * 8;
            __builtin_amdgcn_global_load_lds(
                (const AS1 unsigned int*)g,
                (AS3 unsigned int*)(&slab[bb][(q * 512 + wv * 64) * 8]), 16, 0, 0);
        }
    };

    // ---- prologue: slab 0 ----
    if constexpr (MODE == 1) { loadA1(0); writeA1(0); }
    else                     { stage2(0, 0); }
    __syncthreads();

    // ---- m-loop: 8 tiles of 32 rows ----
#pragma unroll
    for (int mt = 0; mt < 8; ++mt) {
        const int cur = mt & 1, nxt = cur ^ 1;

        // issue next slab's global loads (fly under this tile's MFMAs)
        if (mt < 7) {
            if constexpr (MODE == 1) loadA1(mt + 1);
            else                     stage2(nxt, mt + 1);
        }

        // full-K register compute: 16 kfrags x (2 ds_read + 4 MFMA)
        f32x4 acc[2][2] = {};
        const __bf16* sl = &slab[cur][0];
#pragma unroll
        for (int kf = 0; kf < 16; ++kf) {
            int r0 = (lane & 15), r1 = 16 + (lane & 15);
            int c  = kf * 4 + (lane >> 4);
            bf16x8 a0 = *(const bf16x8*)&sl[r0 * DD + (c ^ (r0 & 7)) * 8];
            bf16x8 a1 = *(const bf16x8*)&sl[r1 * DD + (c ^ (r1 & 7)) * 8];
            acc[0][0] = __builtin_amdgcn_mfma_f32_16x16x32_bf16(a0, wf[0][kf], acc[0][0], 0, 0, 0);
            acc[0][1] = __builtin_amdgcn_mfma_f32_16x16x32_bf16(a0, wf[1][kf], acc[0][1], 0, 0, 0);
            acc[1][0] = __builtin_amdgcn_mfma_f32_16x16x32_bf16(a1, wf[0][kf], acc[1][0], 0, 0, 0);
            acc[1][1] = __builtin_amdgcn_mfma_f32_16x16x32_bf16(a1, wf[1][kf], acc[1][1], 0, 0, 0);
        }

        // epilogue for this 32x32 wave tile
#pragma unroll
        for (int R = 0; R < 2; ++R)
#pragma unroll
            for (int C = 0; C < 2; ++C) {
                int col  = colbase + C * 16 + (lane & 15);
                int rowb = mbase + mt * 32 + R * 16 + ((lane >> 4) << 2);
                float ss = C ? s1 : s0, tt = C ? t1 : t0;
#pragma unroll
                for (int j = 0; j < 4; ++j) {
                    float x = acc[R][C][j];
                    if constexpr (MODE == 1) {
                        x = x * ss + tt;
                        x = (x >= 0.0f) ? x : al * x;
                    }
                    Cout[(size_t)(rowb + j) * DD + col] = (__bf16)x;
                }
            }

        // MODE1: convert+write next slab (after MFMA so fa's vmcnt hid under compute)
        if constexpr (MODE == 1) {
            if (mt < 7) writeA1(nxt);
        }

        __syncthreads();   // vmcnt/lgkm drain ~free: staged a full m-tile ago
    }
}

// ---------------- fused gather (deg-weighted) + bias + PReLU + L2 norm + residual ----------------
// xws is UNSCALED xw; per-source dinv applied here as FMA (wave-uniform scalar).
__global__ __launch_bounds__(256) void k_gather_final(
    const int* __restrict__ offs, const int* __restrict__ csr,
    const __bf16* __restrict__ xws, const float* __restrict__ dinv,
    const float* __restrict__ bg, const float* __restrict__ alpha2,
    const float* __restrict__ text, float* __restrict__ out)
{
    int blk = blockIdx.x;                              // 0..8191
    int sb  = ((blk & 7) << 10) + (blk >> 3);          // XCD-chunked (bijective)
    int wave = threadIdx.x >> 6;
    int lane = threadIdx.x & 63;
    int node = sb * 4 + wave;
    int c = lane * 8;
    int beg = offs[node], end = offs[node + 1];
    int ne = end - beg;

    float dn = dinv[node];
    bf16x8 sv = *(const bf16x8*)(xws + (size_t)node * DD + c);   // self loop
    float a[8];
#pragma unroll
    for (int i = 0; i < 8; ++i) a[i] = dn * (float)sv[i];

    int k = 0;
    for (; k + 4 <= ne; k += 4) {
        int s0 = csr[beg + k + 0];
        int s1 = csr[beg + k + 1];
        int s2 = csr[beg + k + 2];
        int s3 = csr[beg + k + 3];
        float d0 = dinv[s0], d1 = dinv[s1], d2 = dinv[s2], d3 = dinv[s3];
        bf16x8 v0 = *(const bf16x8*)(xws + (size_t)s0 * DD + c);
        bf16x8 v1 = *(const bf16x8*)(xws + (size_t)s1 * DD + c);
        bf16x8 v2 = *(const bf16x8*)(xws + (size_t)s2 * DD + c);
        bf16x8 v3 = *(const bf16x8*)(xws + (size_t)s3 * DD + c);
#pragma unroll
        for (int i = 0; i < 8; ++i)
            a[i] += d0 * (float)v0[i] + d1 * (float)v1[i] + d2 * (float)v2[i] + d3 * (float)v3[i];
    }
    for (; k < ne; ++k) {
        int s = csr[beg + k];
        float ds_ = dinv[s];
        bf16x8 v = *(const bf16x8*)(xws + (size_t)s * DD + c);
#pragma unroll
        for (int i = 0; i < 8; ++i) a[i] += ds_ * (float)v[i];
    }

    float al = alpha2[0];
    float g[8];
    float ss = 0.0f;
#pragma unroll
    for (int i = 0; i < 8; ++i) {
        float x = a[i] * dn + bg[c + i];
        x = (x >= 0.0f) ? x : al * x;
        g[i] = x;
        ss += x * x;
    }
#pragma unroll
    for (int off = 1; off < 64; off <<= 1) ss += __shfl_xor(ss, off, 64);
    float inv = 1.0f / fmaxf(sqrtf(ss), 1e-12f);

    float4 t0 = *(const float4*)(text + (size_t)node * DD + c);
    float4 t1 = *(const float4*)(text + (size_t)node * DD + c + 4);
    float4 o0, o1;
    o0.x = g[0] * inv + t0.x; o0.y = g[1] * inv + t0.y;
    o0.z = g[2] * inv + t0.z; o0.w = g[3] * inv + t0.w;
    o1.x = g[4] * inv + t1.x; o1.y = g[5] * inv + t1.y;
    o1.z = g[6] * inv + t1.z; o1.w = g[7] * inv + t1.w;
    *(float4*)(out + (size_t)node * DD + c)     = o0;
    *(float4*)(out + (size_t)node * DD + c + 4) = o1;
}

extern "C" void kernel_launch(void* const* d_in, const int* in_sizes, int n_in,
                              void* d_out, int out_size, void* d_ws, size_t ws_size,
                              hipStream_t stream) {
    const float* text   = (const float*)d_in[0];
    const int*   esrc   = (const int*)d_in[1];
    const int*   edst   = (const int*)d_in[2];
    const float* W1     = (const float*)d_in[3];
    const float* b1     = (const float*)d_in[4];
    const float* gamma  = (const float*)d_in[5];
    const float* beta   = (const float*)d_in[6];
    const float* rmean  = (const float*)d_in[7];
    const float* rvar   = (const float*)d_in[8];
    const float* alpha1 = (const float*)d_in[9];
    const float* Wg     = (const float*)d_in[10];
    const float* bg     = (const float*)d_in[11];
    const float* alpha2 = (const float*)d_in[12];
    float* out = (float*)d_out;

    // workspace layout (~66.5 MiB)
    char* p = (char*)d_ws;
    auto alloc = [&](size_t bytes) { char* r = p; p += (bytes + 255) & ~(size_t)255; return r; };
    int*    cnt     = (int*)alloc((size_t)NN * 4);
    int*    offs    = (int*)alloc((size_t)(NN + 1) * 4);
    int*    cursor  = (int*)alloc((size_t)NN * 4);
    float*  dinv    = (float*)alloc((size_t)NN * 4);
    int*    csr     = (int*)alloc((size_t)EE * 4);
    __bf16* W1t     = (__bf16*)alloc((size_t)DD * DD * 2);
    __bf16* Wgt     = (__bf16*)alloc((size_t)DD * DD * 2);
    __bf16* h_bf    = (__bf16*)alloc((size_t)NN * DD * 2);
    __bf16* xws     = (__bf16*)alloc((size_t)NN * DD * 2);

    // 1) CSR build + dinv
    k_zero<<<NN / 256, 256, 0, stream>>>(cnt);
    k_count<<<EE / 256, 256, 0, stream>>>(edst, cnt);
    k_scan<<<1, 1024, 0, stream>>>(cnt, offs, cursor, dinv);
    k_fill<<<EE / 256, 256, 0, stream>>>(esrc, edst, cursor, csr);

    // 2) weights -> bf16 [n][k]
    k_wt<<<dim3(16, 16, 2), dim3(32, 8), 0, stream>>>(W1, Wg, W1t, Wgt);

    // 3) h = PReLU(BN(text@W1 + b1))   [weight-stationary, fp32 A inline-cvt]
    k_gemm_w<1><<<256, 512, 0, stream>>>(text, W1t, h_bf, b1, gamma, beta, rmean, rvar, alpha1);

    // 4) xws = h@Wg                    [weight-stationary, unscaled bf16 out]
    k_gemm_w<2><<<256, 512, 0, stream>>>(h_bf, Wgt, xws, nullptr, nullptr, nullptr, nullptr, nullptr, nullptr);

    // 5) fused gather (deg-weighted) + epilogue + L2 norm + residual
    k_gather_final<<<NN / 4, 256, 0, stream>>>(offs, csr, xws, dinv, bg, alpha2, text, out);
}